// Round 5
// baseline (365.713 us; speedup 1.0000x reference)
//
#include <hip/hip_runtime.h>
#include <hip/hip_bf16.h>
#include <stdint.h>

// Problem constants (L=512, B=32, E=1024, H=16, hd=64)
#define LSEQ 512
#define BATCH 32
#define EMB 1024
#define NHEAD 16
#define HDIM 64
#define TOK (LSEQ*BATCH)       // 16384
#define BHTOT (BATCH*NHEAD)    // 512

typedef __attribute__((ext_vector_type(8))) short short8;   // 8 bf16 (4 VGPR)
typedef __attribute__((ext_vector_type(4))) short short4v;  // 4 bf16
typedef __attribute__((ext_vector_type(4))) float f32x4;

// native RNE f32->bf16 (compiler emits packed v_cvt_pk_bf16_f32 — m240)
__device__ __forceinline__ short f2bf(float f) {
  __hip_bfloat16 h = __float2bfloat16(f);
  union { __hip_bfloat16 h; short s; } u; u.h = h;
  return u.s;
}

__device__ __forceinline__ short8 cvt8(f32x4 x0, f32x4 x1) {
  short8 o;
  o[0] = f2bf(x0[0]); o[1] = f2bf(x0[1]); o[2] = f2bf(x0[2]); o[3] = f2bf(x0[3]);
  o[4] = f2bf(x1[0]); o[5] = f2bf(x1[1]); o[6] = f2bf(x1[2]); o[7] = f2bf(x1[3]);
  return o;
}

#if defined(__has_builtin)
#if __has_builtin(__builtin_amdgcn_global_load_lds)
#define HAVE_GLL 1
#endif
#endif

__device__ __forceinline__ void gload_lds16(const void* g, void* l) {
#ifdef HAVE_GLL
  __builtin_amdgcn_global_load_lds((const __attribute__((address_space(1))) void*)g,
                                   (__attribute__((address_space(3))) void*)l, 16, 0, 0);
#else
  *(short8*)l = *(const short8*)g;
#endif
}

// ---------------- cast weights (fold 1/8 q-scale into Wq and bias) ----------------
__global__ void cast_weights(const float* __restrict__ W, const float* __restrict__ Wo,
                             const float* __restrict__ bias,
                             short* __restrict__ Wb, short* __restrict__ Wob,
                             float* __restrict__ biasp)
{
  int i = blockIdx.x * 256 + threadIdx.x;   // float4 index; 786432 (W) + 262144 (Wo)
  if (i < 786432) {
    f32x4 v = ((const f32x4*)W)[i];
    int row = i >> 8;                       // /256 float4 per row of 1024
    float s = (row < 1024) ? 0.125f : 1.0f; // 1/sqrt(64) folded into Wq
    short4v o;
    o[0] = f2bf(v[0]*s); o[1] = f2bf(v[1]*s); o[2] = f2bf(v[2]*s); o[3] = f2bf(v[3]*s);
    ((short4v*)Wb)[i] = o;
  } else {
    int j = i - 786432;
    f32x4 v = ((const f32x4*)Wo)[j];
    short4v o;
    o[0] = f2bf(v[0]); o[1] = f2bf(v[1]); o[2] = f2bf(v[2]); o[3] = f2bf(v[3]);
    ((short4v*)Wob)[j] = o;
  }
  if (i < 768) {                            // 3072 bias floats
    f32x4 v = ((const f32x4*)bias)[i];
    float s = (i < 256) ? 0.125f : 1.0f;
    f32x4 o = {v[0]*s, v[1]*s, v[2]*s, v[3]*s};
    ((f32x4*)biasp)[i] = o;
  }
}

// ---------------- mask (int32 0/1) -> bitmask, 1 bit/elem via ballot ----------------
__global__ void maskbits_kernel(const int* __restrict__ mask, uint32_t* __restrict__ mb)
{
  int w = (blockIdx.x * 256 + threadIdx.x) >> 6;   // row id 0..16383 (= b*512 + l)
  int lane = threadIdx.x & 63;
  const int* src = mask + ((size_t)w << 9);
  uint32_t* dst = mb + w * 16;
  #pragma unroll
  for (int c = 0; c < 8; ++c) {
    int v = src[c * 64 + lane];
    unsigned long long m = __ballot(v != 0);
    if (lane == 0) dst[c*2]     = (uint32_t)m;
    if (lane == 1) dst[c*2 + 1] = (uint32_t)(m >> 32);
  }
}

// ---------------- in-projection GEMM: C[t, headmajor] = bf16(x @ W^T + b) ----------------
// 128x128 tile, BK=32, 4 waves, 16x16x32 bf16 MFMA.
// 2-phase double-buffered LDS (T3 minimum recipe): issue next-tile staging
// BEFORE current-tile ds_read+MFMA; ONE barrier per K-step. A (f32) is
// reg-staged (load early, cvt+ds_write after MFMA = T14 split); B via
// global_load_lds with pre-swizzled source. Swizzle s(row)=(row>>1)&3.
__launch_bounds__(256, 4)
__global__ void proj_gemm(const float* __restrict__ Aq, const float* __restrict__ Ak,
                          const float* __restrict__ Av, const short* __restrict__ W,
                          const float* __restrict__ biasp,
                          short* __restrict__ qh, short* __restrict__ kh,
                          short* __restrict__ vh)
{
  int z = blockIdx.z;
  const float* A = (z == 0) ? Aq : (z == 1) ? Ak : Av;
  short* C       = (z == 0) ? qh : (z == 1) ? kh : vh;
  const short* B = W + (size_t)z * 1024 * 1024;
  const float* bp = biasp + z * 1024;

  // bijective XCD swizzle: the 8 bn-blocks sharing an A panel land on one XCD
  int flat = blockIdx.y * 8 + blockIdx.x;          // 0..1023
  int X = flat & 7, s = flat >> 3;
  int m0 = (X * 16 + (s >> 3)) * 128;
  int n0 = (s & 7) * 128;

  __shared__ alignas(16) short As[2][128 * 32];
  __shared__ alignas(16) short Bs[2][128 * 32];

  const int tid = threadIdx.x, lane = tid & 63;
  const int w = tid >> 6;
  const int wm = (w >> 1) * 64, wn = (w & 1) * 64;
  const int l15 = lane & 15, l4 = lane >> 4;

  // per-thread staging coords (jj = 0,1): 16B chunk ch = tid + jj*256
  const float* aSrc[2];
  const short* bSrc[2];
  int aDst[2], bDst[2];
  #pragma unroll
  for (int jj = 0; jj < 2; ++jj) {
    int ch = tid + jj * 256;
    int row = ch >> 2, cl = ch & 3;
    int cs = cl ^ ((row >> 1) & 3);
    aSrc[jj] = A + (size_t)(m0 + row) * 1024 + cl * 8;   // global at cl, LDS at cs
    bSrc[jj] = B + (size_t)(n0 + row) * 1024 + cs * 8;   // pre-swizzled source, linear dest
    aDst[jj] = row * 32 + cs * 8;
    bDst[jj] = ch * 8;
  }

  f32x4 acc[4][4];
  #pragma unroll
  for (int mi = 0; mi < 4; ++mi)
    #pragma unroll
    for (int ni = 0; ni < 4; ++ni) acc[mi][ni] = f32x4{0.f, 0.f, 0.f, 0.f};

  // prologue: stage k0=0 into buffer 0
  #pragma unroll
  for (int jj = 0; jj < 2; ++jj) {
    f32x4 x0 = *(const f32x4*)(aSrc[jj]);
    f32x4 x1 = *(const f32x4*)(aSrc[jj] + 4);
    *(short8*)&As[0][aDst[jj]] = cvt8(x0, x1);
    gload_lds16(bSrc[jj], &Bs[0][bDst[jj]]);
  }
  __syncthreads();

  int cur = 0;
  for (int k0 = 0; k0 < 1024; k0 += 32) {
    const int nxt = cur ^ 1;
    const bool has_next = (k0 + 32) < 1024;

    // 1. issue next-tile staging EARLY (loads fly under ds_read+MFMA)
    f32x4 xa0[2], xa1[2];
    if (has_next) {
      #pragma unroll
      for (int jj = 0; jj < 2; ++jj) {
        xa0[jj] = *(const f32x4*)(aSrc[jj] + k0 + 32);
        xa1[jj] = *(const f32x4*)(aSrc[jj] + k0 + 36);
        gload_lds16(bSrc[jj] + k0 + 32, &Bs[nxt][bDst[jj]]);
      }
    }

    // 2. fragment reads from current buffer
    short8 af[4], bfr[4];
    #pragma unroll
    for (int mi = 0; mi < 4; ++mi) {
      int row = wm + mi * 16 + l15;
      int cs = l4 ^ ((row >> 1) & 3);
      af[mi] = *(const short8*)&As[cur][row * 32 + cs * 8];
    }
    #pragma unroll
    for (int ni = 0; ni < 4; ++ni) {
      int row = wn + ni * 16 + l15;
      int cs = l4 ^ ((row >> 1) & 3);
      bfr[ni] = *(const short8*)&Bs[cur][row * 32 + cs * 8];
    }

    // 3. MFMA
    #pragma unroll
    for (int mi = 0; mi < 4; ++mi)
      #pragma unroll
      for (int ni = 0; ni < 4; ++ni)
        acc[mi][ni] = __builtin_amdgcn_mfma_f32_16x16x32_bf16(af[mi], bfr[ni], acc[mi][ni], 0, 0, 0);

    // 4. A: cvt + ds_write into next buffer (after MFMA — loads had time to land)
    if (has_next) {
      #pragma unroll
      for (int jj = 0; jj < 2; ++jj)
        *(short8*)&As[nxt][aDst[jj]] = cvt8(xa0[jj], xa1[jj]);
    }

    // 5. single barrier per K-step (drains vmcnt+lgkmcnt; flips buffers)
    __syncthreads();
    cur = nxt;
  }

  // epilogue: head-major bf16  dst[((b*H+h)*512 + lseq)*64 + d]
  #pragma unroll
  for (int ni = 0; ni < 4; ++ni) {
    int gcol = n0 + wn + ni * 16 + l15;
    float bv = bp[gcol];
    int h = gcol >> 6, d = gcol & 63;
    #pragma unroll
    for (int mi = 0; mi < 4; ++mi) {
      int growb = m0 + wm + mi * 16 + l4 * 4;
      #pragma unroll
      for (int r = 0; r < 4; ++r) {
        int grow = growb + r;                 // token index t = lseq*32 + b
        int lsq = grow >> 5, bb = grow & 31;
        C[((size_t)((bb * NHEAD + h) * LSEQ + lsq)) * HDIM + d] = f2bf(acc[mi][ni][r] + bv);
      }
    }
  }
}

// ---------------- flash attention: 1 WG = (b,h, 64 q rows); 4 waves x 16 rows ----------------
__launch_bounds__(256, 2)
__global__ void attn_kernel(const short* __restrict__ qh, const short* __restrict__ kh,
                            const short* __restrict__ vh, const uint32_t* __restrict__ mb,
                            short* __restrict__ ao)
{
  int flat = blockIdx.y * 8 + blockIdx.x;      // 0..4095
  int X = flat & 7, s = flat >> 3;
  int bh = X * 64 + (s >> 3);                  // 8 qblks of same bh share one XCD L2
  int qblk = s & 7;
  int b = bh >> 4, h = bh & 15;
  int q0 = qblk * 64;

  const int tid = threadIdx.x, lane = tid & 63, w = tid >> 6;
  const int l15 = lane & 15, l4 = lane >> 4;

  __shared__ alignas(16) short Ks[64 * 64];        // [kv][d], chunk-XOR swizzled
  __shared__ alignas(16) short Vt[64 * 72];        // [d][kv], pad 72 (2-way banks)
  __shared__ alignas(16) short Ps[4 * 16 * 72];    // per-wave P, pad 72
  __shared__ uint32_t Mw[64 * 2];

  const size_t bhoff = (size_t)bh * (LSEQ * HDIM);

  // Q fragments in registers (1/8 scale already folded into W/bias)
  short8 aq[2];
  {
    int qrow = q0 + w * 16 + l15;
    const short* qp = qh + bhoff + (size_t)qrow * HDIM + l4 * 8;
    aq[0] = *(const short8*)qp;
    aq[1] = *(const short8*)(qp + 32);
  }

  f32x4 oacc[4];
  #pragma unroll
  for (int n = 0; n < 4; ++n) oacc[n] = f32x4{0.f, 0.f, 0.f, 0.f};
  float m_i[4], l_i[4];
  #pragma unroll
  for (int r = 0; r < 4; ++r) { m_i[r] = -1e30f; l_i[r] = 0.f; }

  for (int kt = 0; kt < 8; ++kt) {
    __syncthreads();
    // stage K [64][64] with XOR-swizzled source (linear LDS dest for gload_lds)
    #pragma unroll
    for (int jj = 0; jj < 2; ++jj) {
      int ch = tid + jj * 256;               // 0..511, 16B chunks
      int row = ch >> 3, cl = ch & 7;
      int cg = cl ^ (row & 7);
      const short* g = kh + bhoff + (size_t)(kt * 64 + row) * HDIM + cg * 8;
      gload_lds16(g, &Ks[ch * 8]);
    }
    // stage V transposed: Vt[d][kv]
    #pragma unroll
    for (int jj = 0; jj < 2; ++jj) {
      int c = tid + jj * 256;
      int kv = c & 63, d0 = (c >> 6) * 8;
      const short* g = vh + bhoff + (size_t)(kt * 64 + kv) * HDIM + d0;
      short8 vv = *(const short8*)g;
      #pragma unroll
      for (int j = 0; j < 8; ++j) Vt[(d0 + j) * 72 + kv] = vv[j];
    }
    // stage mask words: 64 q-rows x 2 words (64 kv bits)
    if (tid < 128) {
      int qr = tid >> 1, wd = tid & 1;
      Mw[qr * 2 + wd] = mb[((size_t)b * LSEQ + q0 + qr) * 16 + kt * 2 + wd];
    }
    __syncthreads();

    // S = Q @ K^T   (16 q rows x 64 kv per wave)
    f32x4 sa[4];
    #pragma unroll
    for (int n = 0; n < 4; ++n) sa[n] = f32x4{0.f, 0.f, 0.f, 0.f};
    #pragma unroll
    for (int ss = 0; ss < 2; ++ss) {
      #pragma unroll
      for (int n = 0; n < 4; ++n) {
        int row = n * 16 + l15;
        int cs = (ss * 4 + l4) ^ (row & 7);
        short8 bk = *(const short8*)&Ks[row * 64 + cs * 8];
        sa[n] = __builtin_amdgcn_mfma_f32_16x16x32_bf16(aq[ss], bk, sa[n], 0, 0, 0);
      }
    }

    // mask + online softmax (rows r -> q row 4*l4+r), P -> LDS bf16
    #pragma unroll
    for (int r = 0; r < 4; ++r) {
      int qr = w * 16 + l4 * 4 + r;
      uint32_t mlo = Mw[qr * 2], mhi = Mw[qr * 2 + 1];
      float sv[4];
      #pragma unroll
      for (int n = 0; n < 4; ++n) {
        int cc = n * 16 + l15;
        uint32_t bit = ((cc < 32 ? (mlo >> cc) : (mhi >> (cc - 32))) & 1u);
        sv[n] = bit ? -1e9f : sa[n][r];
      }
      float rmax = fmaxf(fmaxf(sv[0], sv[1]), fmaxf(sv[2], sv[3]));
      #pragma unroll
      for (int off = 1; off < 16; off <<= 1) rmax = fmaxf(rmax, __shfl_xor(rmax, off, 64));
      float mn = fmaxf(m_i[r], rmax);
      float sc = __expf(m_i[r] - mn);
      float p0 = __expf(sv[0] - mn), p1 = __expf(sv[1] - mn);
      float p2 = __expf(sv[2] - mn), p3 = __expf(sv[3] - mn);
      float rs = p0 + p1 + p2 + p3;
      #pragma unroll
      for (int off = 1; off < 16; off <<= 1) rs += __shfl_xor(rs, off, 64);
      l_i[r] = l_i[r] * sc + rs;
      m_i[r] = mn;
      #pragma unroll
      for (int n = 0; n < 4; ++n) oacc[n][r] *= sc;
      short* pp = &Ps[w * 1152 + (l4 * 4 + r) * 72];
      pp[0 * 16 + l15] = f2bf(p0);
      pp[1 * 16 + l15] = f2bf(p1);
      pp[2 * 16 + l15] = f2bf(p2);
      pp[3 * 16 + l15] = f2bf(p3);
    }

    // O += P @ V
    #pragma unroll
    for (int ss = 0; ss < 2; ++ss) {
      short8 pa = *(const short8*)&Ps[w * 1152 + l15 * 72 + ss * 32 + l4 * 8];
      #pragma unroll
      for (int n = 0; n < 4; ++n) {
        short8 bv = *(const short8*)&Vt[(n * 16 + l15) * 72 + ss * 32 + l4 * 8];
        oacc[n] = __builtin_amdgcn_mfma_f32_16x16x32_bf16(pa, bv, oacc[n], 0, 0, 0);
      }
    }
  }

  // epilogue: ao[t][h*64+d], t = qrow*32 + b
  #pragma unroll
  for (int r = 0; r < 4; ++r) {
    float inv = 1.0f / l_i[r];
    int qrow = q0 + w * 16 + l4 * 4 + r;
    size_t tbase = ((size_t)qrow * BATCH + b) * EMB + h * HDIM;
    #pragma unroll
    for (int n = 0; n < 4; ++n)
      ao[tbase + n * 16 + l15] = f2bf(oacc[n][r] * inv);
  }
}

// ---------------- out-projection GEMM: f32 out = ao(bf16) @ Wo^T + bo ----------------
// Same 2-phase double-buffer; both operands via global_load_lds.
__launch_bounds__(256, 4)
__global__ void out_gemm(const short* __restrict__ Ab, const short* __restrict__ W,
                         const float* __restrict__ bo, float* __restrict__ out)
{
  int flat = blockIdx.y * 8 + blockIdx.x;
  int X = flat & 7, s = flat >> 3;
  int m0 = (X * 16 + (s >> 3)) * 128;
  int n0 = (s & 7) * 128;

  __shared__ alignas(16) short As[2][128 * 32];
  __shared__ alignas(16) short Bs[2][128 * 32];

  const int tid = threadIdx.x, lane = tid & 63;
  const int w = tid >> 6;
  const int wm = (w >> 1) * 64, wn = (w & 1) * 64;
  const int l15 = lane & 15, l4 = lane >> 4;

  const short* aSrc[2];
  const short* bSrc[2];
  int sDst[2];
  #pragma unroll
  for (int jj = 0; jj < 2; ++jj) {
    int ch = tid + jj * 256;
    int row = ch >> 2, cl = ch & 3;
    int cs = cl ^ ((row >> 1) & 3);
    aSrc[jj] = Ab + (size_t)(m0 + row) * 1024 + cs * 8;
    bSrc[jj] = W + (size_t)(n0 + row) * 1024 + cs * 8;
    sDst[jj] = ch * 8;
  }

  f32x4 acc[4][4];
  #pragma unroll
  for (int mi = 0; mi < 4; ++mi)
    #pragma unroll
    for (int ni = 0; ni < 4; ++ni) acc[mi][ni] = f32x4{0.f, 0.f, 0.f, 0.f};

  // prologue
  #pragma unroll
  for (int jj = 0; jj < 2; ++jj) {
    gload_lds16(aSrc[jj], &As[0][sDst[jj]]);
    gload_lds16(bSrc[jj], &Bs[0][sDst[jj]]);
  }
  __syncthreads();

  int cur = 0;
  for (int k0 = 0; k0 < 1024; k0 += 32) {
    const int nxt = cur ^ 1;
    const bool has_next = (k0 + 32) < 1024;

    if (has_next) {
      #pragma unroll
      for (int jj = 0; jj < 2; ++jj) {
        gload_lds16(aSrc[jj] + k0 + 32, &As[nxt][sDst[jj]]);
        gload_lds16(bSrc[jj] + k0 + 32, &Bs[nxt][sDst[jj]]);
      }
    }

    short8 af[4], bfr[4];
    #pragma unroll
    for (int mi = 0; mi < 4; ++mi) {
      int row = wm + mi * 16 + l15;
      int cs = l4 ^ ((row >> 1) & 3);
      af[mi] = *(const short8*)&As[cur][row * 32 + cs * 8];
    }
    #pragma unroll
    for (int ni = 0; ni < 4; ++ni) {
      int row = wn + ni * 16 + l15;
      int cs = l4 ^ ((row >> 1) & 3);
      bfr[ni] = *(const short8*)&Bs[cur][row * 32 + cs * 8];
    }
    #pragma unroll
    for (int mi = 0; mi < 4; ++mi)
      #pragma unroll
      for (int ni = 0; ni < 4; ++ni)
        acc[mi][ni] = __builtin_amdgcn_mfma_f32_16x16x32_bf16(af[mi], bfr[ni], acc[mi][ni], 0, 0, 0);

    __syncthreads();
    cur = nxt;
  }

  #pragma unroll
  for (int ni = 0; ni < 4; ++ni) {
    int gcol = n0 + wn + ni * 16 + l15;
    float bv = bo[gcol];
    #pragma unroll
    for (int mi = 0; mi < 4; ++mi) {
      int growb = m0 + wm + mi * 16 + l4 * 4;
      #pragma unroll
      for (int r = 0; r < 4; ++r)
        out[(size_t)(growb + r) * 1024 + gcol] = acc[mi][ni][r] + bv;
    }
  }
}

extern "C" void kernel_launch(void* const* d_in, const int* in_sizes, int n_in,
                              void* d_out, int out_size, void* d_ws, size_t ws_size,
                              hipStream_t stream) {
  const float* q_in = (const float*)d_in[0];
  const float* k_in = (const float*)d_in[1];
  const float* v_in = (const float*)d_in[2];
  const int*   mask = (const int*)d_in[3];
  const float* Wp   = (const float*)d_in[4];
  const float* bp   = (const float*)d_in[5];
  const float* Wo   = (const float*)d_in[6];
  const float* bo   = (const float*)d_in[7];
  // d_in[8] = num_heads (==16, hardcoded)

  char* ws = (char*)d_ws;
  short* Wb    = (short*)ws;    ws += (size_t)3072 * 1024 * 2;
  short* Wob   = (short*)ws;    ws += (size_t)1024 * 1024 * 2;
  float* biasp = (float*)ws;    ws += (size_t)3072 * 4;
  short* qh    = (short*)ws;    ws += (size_t)TOK * EMB * 2;
  short* kh    = (short*)ws;    ws += (size_t)TOK * EMB * 2;
  short* vh    = (short*)ws;    ws += (size_t)TOK * EMB * 2;
  short* ao    = (short*)ws;    ws += (size_t)TOK * EMB * 2;
  uint32_t* mb = (uint32_t*)ws; ws += (size_t)BATCH * LSEQ * 16 * 4;

  cast_weights<<<4096, 256, 0, stream>>>(Wp, Wo, bp, Wb, Wob, biasp);
  maskbits_kernel<<<4096, 256, 0, stream>>>(mask, mb);
  proj_gemm<<<dim3(8, 128, 3), 256, 0, stream>>>(q_in, k_in, v_in, Wb, biasp, qh, kh, vh);
  attn_kernel<<<dim3(8, 512), 256, 0, stream>>>(qh, kh, vh, mb, ao);
  out_gemm<<<dim3(8, 128), 256, 0, stream>>>(ao, Wob, bo, (float*)d_out);
}

// Round 7
// 362.411 us; speedup vs baseline: 1.0091x; 1.0091x over previous
//
#include <hip/hip_runtime.h>
#include <hip/hip_bf16.h>
#include <stdint.h>

// Problem constants (L=512, B=32, E=1024, H=16, hd=64)
#define LSEQ 512
#define BATCH 32
#define EMB 1024
#define NHEAD 16
#define HDIM 64
#define TOK (LSEQ*BATCH)       // 16384
#define BHTOT (BATCH*NHEAD)    // 512

typedef __attribute__((ext_vector_type(8))) short short8;   // 8 bf16 (4 VGPR)
typedef __attribute__((ext_vector_type(4))) short short4v;  // 4 bf16
typedef __attribute__((ext_vector_type(4))) float f32x4;

// native RNE f32->bf16 (compiler emits packed v_cvt_pk_bf16_f32 — m240)
__device__ __forceinline__ short f2bf(float f) {
  __hip_bfloat16 h = __float2bfloat16(f);
  union { __hip_bfloat16 h; short s; } u; u.h = h;
  return u.s;
}

__device__ __forceinline__ short8 cvt8(f32x4 x0, f32x4 x1) {
  short8 o;
  o[0] = f2bf(x0[0]); o[1] = f2bf(x0[1]); o[2] = f2bf(x0[2]); o[3] = f2bf(x0[3]);
  o[4] = f2bf(x1[0]); o[5] = f2bf(x1[1]); o[6] = f2bf(x1[2]); o[7] = f2bf(x1[3]);
  return o;
}

#if defined(__has_builtin)
#if __has_builtin(__builtin_amdgcn_global_load_lds)
#define HAVE_GLL 1
#endif
#endif

__device__ __forceinline__ void gload_lds16(const void* g, void* l) {
#ifdef HAVE_GLL
  __builtin_amdgcn_global_load_lds((const __attribute__((address_space(1))) void*)g,
                                   (__attribute__((address_space(3))) void*)l, 16, 0, 0);
#else
  *(short8*)l = *(const short8*)g;
#endif
}

// counted-waitcnt fences (T4). "memory" clobber pins surrounding mem ops to
// their sub-step; sched_barrier(0) stops hipcc reordering past the asm (rule #18).
#define WAIT_VM6  do { asm volatile("s_waitcnt vmcnt(6)" ::: "memory"); __builtin_amdgcn_sched_barrier(0); } while (0)
#define WAIT_VM4  do { asm volatile("s_waitcnt vmcnt(4)" ::: "memory"); __builtin_amdgcn_sched_barrier(0); } while (0)
#define WAIT_VM0  do { asm volatile("s_waitcnt vmcnt(0)" ::: "memory"); __builtin_amdgcn_sched_barrier(0); } while (0)
#define WAIT_LGKM0 do { asm volatile("s_waitcnt lgkmcnt(0)" ::: "memory"); __builtin_amdgcn_sched_barrier(0); } while (0)
#define BAR() __builtin_amdgcn_s_barrier()

// ---------------- cast weights (fold 1/8 q-scale into Wq and bias) ----------------
__global__ void cast_weights(const float* __restrict__ W, const float* __restrict__ Wo,
                             const float* __restrict__ bias,
                             short* __restrict__ Wb, short* __restrict__ Wob,
                             float* __restrict__ biasp)
{
  int i = blockIdx.x * 256 + threadIdx.x;   // float4 index; 786432 (W) + 262144 (Wo)
  if (i < 786432) {
    f32x4 v = ((const f32x4*)W)[i];
    int row = i >> 8;                       // /256 float4 per row of 1024
    float s = (row < 1024) ? 0.125f : 1.0f; // 1/sqrt(64) folded into Wq
    short4v o;
    o[0] = f2bf(v[0]*s); o[1] = f2bf(v[1]*s); o[2] = f2bf(v[2]*s); o[3] = f2bf(v[3]*s);
    ((short4v*)Wb)[i] = o;
  } else {
    int j = i - 786432;
    f32x4 v = ((const f32x4*)Wo)[j];
    short4v o;
    o[0] = f2bf(v[0]); o[1] = f2bf(v[1]); o[2] = f2bf(v[2]); o[3] = f2bf(v[3]);
    ((short4v*)Wob)[j] = o;
  }
  if (i < 768) {                            // 3072 bias floats
    f32x4 v = ((const f32x4*)bias)[i];
    float s = (i < 256) ? 0.125f : 1.0f;
    f32x4 o = {v[0]*s, v[1]*s, v[2]*s, v[3]*s};
    ((f32x4*)biasp)[i] = o;
  }
}

// ---------------- mask (int32 0/1) -> bitmask, 1 bit/elem via ballot ----------------
__global__ void maskbits_kernel(const int* __restrict__ mask, uint32_t* __restrict__ mb)
{
  int w = (blockIdx.x * 256 + threadIdx.x) >> 6;   // row id 0..16383 (= b*512 + l)
  int lane = threadIdx.x & 63;
  const int* src = mask + ((size_t)w << 9);
  uint32_t* dst = mb + w * 16;
  #pragma unroll
  for (int c = 0; c < 8; ++c) {
    int v = src[c * 64 + lane];
    unsigned long long m = __ballot(v != 0);
    if (lane == 0) dst[c*2]     = (uint32_t)m;
    if (lane == 1) dst[c*2 + 1] = (uint32_t)(m >> 32);
  }
}

// shared fragment-read + MFMA macros (128x128 tile, 4 waves, 16x16x32 bf16)
#define FRAG_READ(AsX, BsX)                                           \
    short8 af[4], bfr[4];                                             \
    _Pragma("unroll")                                                 \
    for (int mi = 0; mi < 4; ++mi) {                                  \
      int row = wm + mi * 16 + l15;                                   \
      int cs = l4 ^ ((row >> 1) & 3);                                 \
      af[mi] = *(const short8*)&AsX[row * 32 + cs * 8];               \
    }                                                                 \
    _Pragma("unroll")                                                 \
    for (int ni = 0; ni < 4; ++ni) {                                  \
      int row = wn + ni * 16 + l15;                                   \
      int cs = l4 ^ ((row >> 1) & 3);                                 \
      bfr[ni] = *(const short8*)&BsX[row * 32 + cs * 8];              \
    }

#define DO_MFMA()                                                     \
    _Pragma("unroll")                                                 \
    for (int mi = 0; mi < 4; ++mi)                                    \
      _Pragma("unroll")                                               \
      for (int ni = 0; ni < 4; ++ni)                                  \
        acc[mi][ni] = __builtin_amdgcn_mfma_f32_16x16x32_bf16(af[mi], bfr[ni], acc[mi][ni], 0, 0, 0)

// ---------------- in-projection GEMM: C[t, headmajor] = bf16(x @ W^T + b) ----------------
// Counted-vmcnt pipeline (T4): raw s_barrier, step s+2 loads stay in flight
// across barrier2 (vmcnt(6) drains only s+1's 6 loads). A (f32) reg-staged
// (cvt after MFMA), B via global_load_lds w/ pre-swizzled source.
// Invariant at loop top: bufs[s&1] ready; B(s+1)[2]+A(s+1)[4] in flight.
__launch_bounds__(256, 3)
__global__ void proj_gemm(const float* __restrict__ Aq, const float* __restrict__ Ak,
                          const float* __restrict__ Av, const short* __restrict__ W,
                          const float* __restrict__ biasp,
                          short* __restrict__ qh, short* __restrict__ kh,
                          short* __restrict__ vh)
{
  int z = blockIdx.z;
  const float* A = (z == 0) ? Aq : (z == 1) ? Ak : Av;
  short* C       = (z == 0) ? qh : (z == 1) ? kh : vh;
  const short* B = W + (size_t)z * 1024 * 1024;
  const float* bp = biasp + z * 1024;

  // bijective XCD swizzle: the 8 n-blocks sharing an A panel land on one XCD
  int flat = blockIdx.y * 8 + blockIdx.x;          // 0..1023
  int X = flat & 7, s0 = flat >> 3;
  int m0 = (X * 16 + (s0 >> 3)) * 128;
  int n0 = (s0 & 7) * 128;

  __shared__ alignas(16) short As0[128 * 32];
  __shared__ alignas(16) short As1[128 * 32];
  __shared__ alignas(16) short Bs0[128 * 32];
  __shared__ alignas(16) short Bs1[128 * 32];

  const int tid = threadIdx.x, lane = tid & 63;
  const int w = tid >> 6;
  const int wm = (w >> 1) * 64, wn = (w & 1) * 64;
  const int l15 = lane & 15, l4 = lane >> 4;

  // per-thread staging coords (jj = 0,1): 16B chunk ch = tid + jj*256
  const float* aSrc[2];
  const short* bSrc[2];
  int aDst[2], bDst[2];
  #pragma unroll
  for (int jj = 0; jj < 2; ++jj) {
    int ch = tid + jj * 256;
    int row = ch >> 2, cl = ch & 3;
    int cs = cl ^ ((row >> 1) & 3);
    aSrc[jj] = A + (size_t)(m0 + row) * 1024 + cl * 8;   // global at cl, LDS at cs
    bSrc[jj] = B + (size_t)(n0 + row) * 1024 + cs * 8;   // pre-swizzled source, linear dest
    aDst[jj] = row * 32 + cs * 8;
    bDst[jj] = ch * 8;
  }

  f32x4 acc[4][4];
  #pragma unroll
  for (int mi = 0; mi < 4; ++mi)
    #pragma unroll
    for (int ni = 0; ni < 4; ++ni) acc[mi][ni] = f32x4{0.f, 0.f, 0.f, 0.f};

  f32x4 ea0[2], ea1[2];   // A regs, even steps
  f32x4 oa0[2], oa1[2];   // A regs, odd steps

  // ---- prologue: stage step 0; issue step 1 ----
  #pragma unroll
  for (int jj = 0; jj < 2; ++jj) {
    gload_lds16(bSrc[jj], &Bs0[bDst[jj]]);
    ea0[jj] = *(const f32x4*)(aSrc[jj]);
    ea1[jj] = *(const f32x4*)(aSrc[jj] + 4);
  }
  #pragma unroll
  for (int jj = 0; jj < 2; ++jj)
    *(short8*)&As0[aDst[jj]] = cvt8(ea0[jj], ea1[jj]);   // auto-waits A(0)
  WAIT_VM0;                                              // B(0) landed in Bs0
  #pragma unroll
  for (int jj = 0; jj < 2; ++jj) {
    gload_lds16(bSrc[jj] + 32, &Bs1[bDst[jj]]);
    oa0[jj] = *(const f32x4*)(aSrc[jj] + 32);
    oa1[jj] = *(const f32x4*)(aSrc[jj] + 36);
  }
  WAIT_LGKM0;   // As0 writes visible
  BAR();        // B(1)+A(1) = 6 loads cross this barrier in flight

  // ---- main loop: 15 iters x 2 steps (s = 0..29); issues up to step 31 ----
  for (int i = 0; i < 15; ++i) {
    const int s = 2 * i;
    { // even step s: read bufs0, issue s+2 -> bufs0, finish A(s+1) -> As1
      FRAG_READ(As0, Bs0);
      WAIT_LGKM0;  // my frags landed
      BAR();       // all waves done reading bufs0
      #pragma unroll
      for (int jj = 0; jj < 2; ++jj) {
        gload_lds16(bSrc[jj] + (s + 2) * 32, &Bs0[bDst[jj]]);
        ea0[jj] = *(const f32x4*)(aSrc[jj] + (s + 2) * 32);
        ea1[jj] = *(const f32x4*)(aSrc[jj] + (s + 2) * 32 + 4);
      }
      DO_MFMA();
      #pragma unroll
      for (int jj = 0; jj < 2; ++jj)
        *(short8*)&As1[aDst[jj]] = cvt8(oa0[jj], oa1[jj]);  // auto-waits A(s+1)
      WAIT_VM6;    // drain B(s+1) (6 newest = B/A(s+2) stay in flight)
      WAIT_LGKM0;  // As1 writes visible
      BAR();
    }
    { // odd step s+1: read bufs1, issue s+3 -> bufs1, finish A(s+2) -> As0
      FRAG_READ(As1, Bs1);
      WAIT_LGKM0;
      BAR();
      #pragma unroll
      for (int jj = 0; jj < 2; ++jj) {
        gload_lds16(bSrc[jj] + (s + 3) * 32, &Bs1[bDst[jj]]);
        oa0[jj] = *(const f32x4*)(aSrc[jj] + (s + 3) * 32);
        oa1[jj] = *(const f32x4*)(aSrc[jj] + (s + 3) * 32 + 4);
      }
      DO_MFMA();
      #pragma unroll
      for (int jj = 0; jj < 2; ++jj)
        *(short8*)&As0[aDst[jj]] = cvt8(ea0[jj], ea1[jj]);  // auto-waits A(s+2)
      WAIT_VM6;    // drain B(s+2)
      WAIT_LGKM0;
      BAR();
    }
  }

  // ---- epilogue: steps 30, 31 (no new issues) ----
  { // step 30: bufs0 ready; finish A(31) -> As1
    FRAG_READ(As0, Bs0);
    DO_MFMA();   // compiler auto-waits lgkm for frags
    #pragma unroll
    for (int jj = 0; jj < 2; ++jj)
      *(short8*)&As1[aDst[jj]] = cvt8(oa0[jj], oa1[jj]);
    WAIT_VM0;    // B(31) landed in Bs1
    WAIT_LGKM0;
    BAR();
  }
  { // step 31
    FRAG_READ(As1, Bs1);
    DO_MFMA();
  }

  // epilogue: head-major bf16  dst[((b*H+h)*512 + lseq)*64 + d]
  #pragma unroll
  for (int ni = 0; ni < 4; ++ni) {
    int gcol = n0 + wn + ni * 16 + l15;
    float bv = bp[gcol];
    int h = gcol >> 6, d = gcol & 63;
    #pragma unroll
    for (int mi = 0; mi < 4; ++mi) {
      int growb = m0 + wm + mi * 16 + l4 * 4;
      #pragma unroll
      for (int r = 0; r < 4; ++r) {
        int grow = growb + r;                 // token index t = lseq*32 + b
        int lsq = grow >> 5, bb = grow & 31;
        C[((size_t)((bb * NHEAD + h) * LSEQ + lsq)) * HDIM + d] = f2bf(acc[mi][ni][r] + bv);
      }
    }
  }
}

// ---------------- flash attention: 1 WG = (b,h, 64 q rows); 4 waves x 16 rows ----------------
__launch_bounds__(256, 2)
__global__ void attn_kernel(const short* __restrict__ qh, const short* __restrict__ kh,
                            const short* __restrict__ vh, const uint32_t* __restrict__ mb,
                            short* __restrict__ ao)
{
  int flat = blockIdx.y * 8 + blockIdx.x;      // 0..4095
  int X = flat & 7, s = flat >> 3;
  int bh = X * 64 + (s >> 3);                  // 8 qblks of same bh share one XCD L2
  int qblk = s & 7;
  int b = bh >> 4, h = bh & 15;
  int q0 = qblk * 64;

  const int tid = threadIdx.x, lane = tid & 63, w = tid >> 6;
  const int l15 = lane & 15, l4 = lane >> 4;

  __shared__ alignas(16) short Ks[64 * 64];        // [kv][d], chunk-XOR swizzled
  __shared__ alignas(16) short Vt[64 * 72];        // [d][kv], pad 72 (2-way banks)
  __shared__ alignas(16) short Ps[4 * 16 * 72];    // per-wave P, pad 72
  __shared__ uint32_t Mw[64 * 2];

  const size_t bhoff = (size_t)bh * (LSEQ * HDIM);

  // Q fragments in registers (1/8 scale already folded into W/bias)
  short8 aq[2];
  {
    int qrow = q0 + w * 16 + l15;
    const short* qp = qh + bhoff + (size_t)qrow * HDIM + l4 * 8;
    aq[0] = *(const short8*)qp;
    aq[1] = *(const short8*)(qp + 32);
  }

  f32x4 oacc[4];
  #pragma unroll
  for (int n = 0; n < 4; ++n) oacc[n] = f32x4{0.f, 0.f, 0.f, 0.f};
  float m_i[4], l_i[4];
  #pragma unroll
  for (int r = 0; r < 4; ++r) { m_i[r] = -1e30f; l_i[r] = 0.f; }

  for (int kt = 0; kt < 8; ++kt) {
    __syncthreads();
    // stage K [64][64] with XOR-swizzled source (linear LDS dest for gload_lds)
    #pragma unroll
    for (int jj = 0; jj < 2; ++jj) {
      int ch = tid + jj * 256;               // 0..511, 16B chunks
      int row = ch >> 3, cl = ch & 7;
      int cg = cl ^ (row & 7);
      const short* g = kh + bhoff + (size_t)(kt * 64 + row) * HDIM + cg * 8;
      gload_lds16(g, &Ks[ch * 8]);
    }
    // stage V transposed: Vt[d][kv]
    #pragma unroll
    for (int jj = 0; jj < 2; ++jj) {
      int c = tid + jj * 256;
      int kv = c & 63, d0 = (c >> 6) * 8;
      const short* g = vh + bhoff + (size_t)(kt * 64 + kv) * HDIM + d0;
      short8 vv = *(const short8*)g;
      #pragma unroll
      for (int j = 0; j < 8; ++j) Vt[(d0 + j) * 72 + kv] = vv[j];
    }
    // stage mask words: 64 q-rows x 2 words (64 kv bits)
    if (tid < 128) {
      int qr = tid >> 1, wd = tid & 1;
      Mw[qr * 2 + wd] = mb[((size_t)b * LSEQ + q0 + qr) * 16 + kt * 2 + wd];
    }
    __syncthreads();

    // S = Q @ K^T   (16 q rows x 64 kv per wave)
    f32x4 sa[4];
    #pragma unroll
    for (int n = 0; n < 4; ++n) sa[n] = f32x4{0.f, 0.f, 0.f, 0.f};
    #pragma unroll
    for (int ss = 0; ss < 2; ++ss) {
      #pragma unroll
      for (int n = 0; n < 4; ++n) {
        int row = n * 16 + l15;
        int cs = (ss * 4 + l4) ^ (row & 7);
        short8 bk = *(const short8*)&Ks[row * 64 + cs * 8];
        sa[n] = __builtin_amdgcn_mfma_f32_16x16x32_bf16(aq[ss], bk, sa[n], 0, 0, 0);
      }
    }

    // mask + online softmax (rows r -> q row 4*l4+r), P -> LDS bf16
    #pragma unroll
    for (int r = 0; r < 4; ++r) {
      int qr = w * 16 + l4 * 4 + r;
      uint32_t mlo = Mw[qr * 2], mhi = Mw[qr * 2 + 1];
      float sv[4];
      #pragma unroll
      for (int n = 0; n < 4; ++n) {
        int cc = n * 16 + l15;
        uint32_t bit = ((cc < 32 ? (mlo >> cc) : (mhi >> (cc - 32))) & 1u);
        sv[n] = bit ? -1e9f : sa[n][r];
      }
      float rmax = fmaxf(fmaxf(sv[0], sv[1]), fmaxf(sv[2], sv[3]));
      #pragma unroll
      for (int off = 1; off < 16; off <<= 1) rmax = fmaxf(rmax, __shfl_xor(rmax, off, 64));
      float mn = fmaxf(m_i[r], rmax);
      float sc = __expf(m_i[r] - mn);
      float p0 = __expf(sv[0] - mn), p1 = __expf(sv[1] - mn);
      float p2 = __expf(sv[2] - mn), p3 = __expf(sv[3] - mn);
      float rs = p0 + p1 + p2 + p3;
      #pragma unroll
      for (int off = 1; off < 16; off <<= 1) rs += __shfl_xor(rs, off, 64);
      l_i[r] = l_i[r] * sc + rs;
      m_i[r] = mn;
      #pragma unroll
      for (int n = 0; n < 4; ++n) oacc[n][r] *= sc;
      short* pp = &Ps[w * 1152 + (l4 * 4 + r) * 72];
      pp[0 * 16 + l15] = f2bf(p0);
      pp[1 * 16 + l15] = f2bf(p1);
      pp[2 * 16 + l15] = f2bf(p2);
      pp[3 * 16 + l15] = f2bf(p3);
    }

    // O += P @ V
    #pragma unroll
    for (int ss = 0; ss < 2; ++ss) {
      short8 pa = *(const short8*)&Ps[w * 1152 + l15 * 72 + ss * 32 + l4 * 8];
      #pragma unroll
      for (int n = 0; n < 4; ++n) {
        short8 bv = *(const short8*)&Vt[(n * 16 + l15) * 72 + ss * 32 + l4 * 8];
        oacc[n] = __builtin_amdgcn_mfma_f32_16x16x32_bf16(pa, bv, oacc[n], 0, 0, 0);
      }
    }
  }

  // epilogue: ao[t][h*64+d], t = qrow*32 + b
  #pragma unroll
  for (int r = 0; r < 4; ++r) {
    float inv = 1.0f / l_i[r];
    int qrow = q0 + w * 16 + l4 * 4 + r;
    size_t tbase = ((size_t)qrow * BATCH + b) * EMB + h * HDIM;
    #pragma unroll
    for (int n = 0; n < 4; ++n)
      ao[tbase + n * 16 + l15] = f2bf(oacc[n][r] * inv);
  }
}

// ---------------- out-projection GEMM: f32 out = ao(bf16) @ Wo^T + bo ----------------
// Same counted-vmcnt pipeline; both operands via global_load_lds (4 loads/step).
__launch_bounds__(256, 4)
__global__ void out_gemm(const short* __restrict__ Ab, const short* __restrict__ W,
                         const float* __restrict__ bo, float* __restrict__ out)
{
  int flat = blockIdx.y * 8 + blockIdx.x;
  int X = flat & 7, s0 = flat >> 3;
  int m0 = (X * 16 + (s0 >> 3)) * 128;
  int n0 = (s0 & 7) * 128;

  __shared__ alignas(16) short As0[128 * 32];
  __shared__ alignas(16) short As1[128 * 32];
  __shared__ alignas(16) short Bs0[128 * 32];
  __shared__ alignas(16) short Bs1[128 * 32];

  const int tid = threadIdx.x, lane = tid & 63;
  const int w = tid >> 6;
  const int wm = (w >> 1) * 64, wn = (w & 1) * 64;
  const int l15 = lane & 15, l4 = lane >> 4;

  const short* aSrc[2];
  const short* bSrc[2];
  int sDst[2];
  #pragma unroll
  for (int jj = 0; jj < 2; ++jj) {
    int ch = tid + jj * 256;
    int row = ch >> 2, cl = ch & 3;
    int cs = cl ^ ((row >> 1) & 3);
    aSrc[jj] = Ab + (size_t)(m0 + row) * 1024 + cs * 8;
    bSrc[jj] = W + (size_t)(n0 + row) * 1024 + cs * 8;
    sDst[jj] = ch * 8;
  }

  f32x4 acc[4][4];
  #pragma unroll
  for (int mi = 0; mi < 4; ++mi)
    #pragma unroll
    for (int ni = 0; ni < 4; ++ni) acc[mi][ni] = f32x4{0.f, 0.f, 0.f, 0.f};

  // prologue: issue step 0 and step 1; drain step 0 only
  #pragma unroll
  for (int jj = 0; jj < 2; ++jj) {
    gload_lds16(aSrc[jj], &As0[sDst[jj]]);
    gload_lds16(bSrc[jj], &Bs0[sDst[jj]]);
  }
  #pragma unroll
  for (int jj = 0; jj < 2; ++jj) {
    gload_lds16(aSrc[jj] + 32, &As1[sDst[jj]]);
    gload_lds16(bSrc[jj] + 32, &Bs1[sDst[jj]]);
  }
  WAIT_VM4;   // step-0's 4 landed; step-1's 4 in flight
  BAR();

  for (int i = 0; i < 15; ++i) {
    const int s = 2 * i;
    { // even step s
      FRAG_READ(As0, Bs0);
      WAIT_LGKM0;
      BAR();
      #pragma unroll
      for (int jj = 0; jj < 2; ++jj) {
        gload_lds16(aSrc[jj] + (s + 2) * 32, &As0[sDst[jj]]);
        gload_lds16(bSrc[jj] + (s + 2) * 32, &Bs0[sDst[jj]]);
      }
      DO_MFMA();
      WAIT_VM4;   // drain s+1's 4; s+2's 4 stay in flight
      BAR();
    }
    { // odd step s+1
      FRAG_READ(As1, Bs1);
      WAIT_LGKM0;
      BAR();
      #pragma unroll
      for (int jj = 0; jj < 2; ++jj) {
        gload_lds16(aSrc[jj] + (s + 3) * 32, &As1[sDst[jj]]);
        gload_lds16(bSrc[jj] + (s + 3) * 32, &Bs1[sDst[jj]]);
      }
      DO_MFMA();
      WAIT_VM4;   // drain s+2's 4
      BAR();
    }
  }

  { // step 30
    FRAG_READ(As0, Bs0);
    DO_MFMA();
    WAIT_VM0;   // step-31's 4 landed
    BAR();
  }
  { // step 31
    FRAG_READ(As1, Bs1);
    DO_MFMA();
  }

  #pragma unroll
  for (int ni = 0; ni < 4; ++ni) {
    int gcol = n0 + wn + ni * 16 + l15;
    float bv = bo[gcol];
    #pragma unroll
    for (int mi = 0; mi < 4; ++mi) {
      int growb = m0 + wm + mi * 16 + l4 * 4;
      #pragma unroll
      for (int r = 0; r < 4; ++r)
        out[(size_t)(growb + r) * 1024 + gcol] = acc[mi][ni][r] + bv;
    }
  }
}

extern "C" void kernel_launch(void* const* d_in, const int* in_sizes, int n_in,
                              void* d_out, int out_size, void* d_ws, size_t ws_size,
                              hipStream_t stream) {
  const float* q_in = (const float*)d_in[0];
  const float* k_in = (const float*)d_in[1];
  const float* v_in = (const float*)d_in[2];
  const int*   mask = (const int*)d_in[3];
  const float* Wp   = (const float*)d_in[4];
  const float* bp   = (const float*)d_in[5];
  const float* Wo   = (const float*)d_in[6];
  const float* bo   = (const float*)d_in[7];
  // d_in[8] = num_heads (==16, hardcoded)

  char* ws = (char*)d_ws;
  short* Wb    = (short*)ws;    ws += (size_t)3072 * 1024 * 2;
  short* Wob   = (short*)ws;    ws += (size_t)1024 * 1024 * 2;
  float* biasp = (float*)ws;    ws += (size_t)3072 * 4;
  short* qh    = (short*)ws;    ws += (size_t)TOK * EMB * 2;
  short* kh    = (short*)ws;    ws += (size_t)TOK * EMB * 2;
  short* vh    = (short*)ws;    ws += (size_t)TOK * EMB * 2;
  short* ao    = (short*)ws;    ws += (size_t)TOK * EMB * 2;
  uint32_t* mb = (uint32_t*)ws; ws += (size_t)BATCH * LSEQ * 16 * 4;

  cast_weights<<<4096, 256, 0, stream>>>(Wp, Wo, bp, Wb, Wob, biasp);
  maskbits_kernel<<<4096, 256, 0, stream>>>(mask, mb);
  proj_gemm<<<dim3(8, 128, 3), 256, 0, stream>>>(q_in, k_in, v_in, Wb, biasp, qh, kh, vh);
  attn_kernel<<<dim3(8, 512), 256, 0, stream>>>(qh, kh, vh, mb, ao);
  out_gemm<<<dim3(8, 128), 256, 0, stream>>>(ao, Wob, bo, (float*)d_out);
}